// Round 4
// baseline (295.219 us; speedup 1.0000x reference)
//
#include <hip/hip_runtime.h>
#include <hip/hip_fp16.h>
#include <stdint.h>

#define M_DIM 64
#define K_DIM 8192
#define N_DIM 28672
#define QGROUP 128

typedef __attribute__((ext_vector_type(4))) float floatx4;
typedef __attribute__((ext_vector_type(8))) _Float16 halfx8;
typedef __attribute__((ext_vector_type(4))) uint32_t uintx4;

// bit_cast via memcpy (works for non-trivially-copyable HIP types)
template <typename T, typename F>
__device__ __forceinline__ T bc(F f) {
  static_assert(sizeof(T) == sizeof(F), "size mismatch");
  T t;
  __builtin_memcpy(&t, &f, sizeof(T));
  return t;
}

// p = two fp16 lanes holding (1024+nib); returns two fp16 of (nib-8)*s
// (1024+nib and 1032 are fp16-exact, same binade -> sub exact; mul RNE =
// exactly the reference's fp16 multiply)
__device__ __forceinline__ uint32_t dq_pair(uint32_t p, uint32_t s2bits) {
  __half2 v = bc<__half2>(p);
  __half2 z = bc<__half2>(0x64086408u);  // (1032, 1032)
  __half2 s = bc<__half2>(s2bits);
  return bc<uint32_t>(__hmul2(__hsub2(v, z), s));
}

// one packed dword (8 nibbles) -> B fragment (8 fp16) for one n, in the
// PERMUTED k-order [0,4,1,5,2,6,3,7]: pair j extracts nibbles (j, j+4) with
// one shift + one v_and_or_b32. Apack uses the same k-order, so the MFMA
// contraction is consistent.
__device__ __forceinline__ halfx8 dequant8(uint32_t q, uint32_t s2bits) {
  const uint32_t MM = 0x000F000Fu;
  const uint32_t MG = 0x64006400u;  // fp16(1024) in both halves
  uintx4 r;
  r.x = dq_pair((q & MM) | MG, s2bits);          // k0 | k4
  r.y = dq_pair(((q >> 4) & MM) | MG, s2bits);   // k1 | k5
  r.z = dq_pair(((q >> 8) & MM) | MG, s2bits);   // k2 | k6
  r.w = dq_pair(((q >> 12) & MM) | MG, s2bits);  // k3 | k7
  return bc<halfx8>(r);
}

// A (fp32, 64x8192, fp16-exact) -> fragment-ordered fp16 pack, with the
// SAME within-8 k-permutation [0,4,1,5,2,6,3,7] as dequant8.
// Apack[((t*4+mf)*64 + l)*8 + j] =
//   (f16) A[(l&15)+16*mf][32*t + 8*(l>>4) + perm[j]]
__global__ __launch_bounds__(256) void pack_a(const float* __restrict__ A,
                                              _Float16* __restrict__ Apack) {
  const int g = (int)blockIdx.x * 256 + (int)threadIdx.x;  // 0 .. 65535
  const int l = g & 63;
  const int mf = (g >> 6) & 3;
  const int t = g >> 8;
  const int row = (l & 15) + 16 * mf;
  const int k0 = 32 * t + 8 * (l >> 4);
  const float* src = A + (size_t)row * K_DIM + k0;
  floatx4 a0 = *(const floatx4*)src;        // k 0..3
  floatx4 a1 = *(const floatx4*)(src + 4);  // k 4..7
  halfx8 hv;
  hv[0] = (_Float16)a0[0]; hv[1] = (_Float16)a1[0];
  hv[2] = (_Float16)a0[1]; hv[3] = (_Float16)a1[1];
  hv[4] = (_Float16)a0[2]; hv[5] = (_Float16)a1[2];
  hv[6] = (_Float16)a0[3]; hv[7] = (_Float16)a1[3];
  *(halfx8*)(Apack + (size_t)g * 8) = hv;
}

// ONE WAVE PER BLOCK (64 threads), wave tile 64m x 128n.
// Rationale (rounds 0-3): per-SIMD wave-step cost is ~1900 cyc INVARIANT to
// occupancy/barriers/dequant-VALU -> the gate is per-CU memory delivery per
// step. So: reuse each A fragment across 8 output columns (A bytes per unit
// of work halved) and halve the number of step boundaries per unit.
// KSPLIT=2 -> grid (224,2) = 448 blocks = 1.75/CU; occupancy buys nothing
// here, so we stop paying partial-traffic for it.
template <int KSLICE, bool SPLIT, bool PACKED>
__global__ __launch_bounds__(64, 2) void wq_mfma(
    const float* __restrict__ A,        // fp32 raw (only used if !PACKED)
    const _Float16* __restrict__ Apack, // fragment-ordered fp16
    const int* __restrict__ qweight,    // int32, K/8 x N
    const float* __restrict__ scales,   // fp32, K/128 x N (fp16-exact)
    const float* __restrict__ bias,     // fp32, N (fp16-exact)
    float* __restrict__ part,           // KSPLIT x M x N (fp32)
    float* __restrict__ out) {          // fp32, M x N
  constexpr int STEPS = KSLICE / 32;
  constexpr int GROUPS = KSLICE / QGROUP;

  const int l = (int)threadIdx.x & 63;
  const int l15 = l & 15;
  const int l4 = l >> 4;
  const int nb = (int)blockIdx.x * 128;
  const int kb = (int)blockIdx.y * KSLICE;
  const int ncol = nb + 4 * l15;  // lane's first n in half 0; half 1 at +64

  const int* qptr = qweight + (size_t)((kb >> 3) + l4) * N_DIM + ncol;
  const float* sptr = scales + (size_t)(kb / QGROUP) * N_DIM + ncol;
  // per-step stride 2048 halves (4 KB); mf at +512 halves (imm offset)
  const _Float16* apt = Apack + ((size_t)(kb >> 5) * 256 + l) * 8;
  // raw-A fallback base (row l15, k = kb + 8*l4); mf at +16 rows
  const float* araw = A + (size_t)l15 * K_DIM + (kb + 8 * l4);

  floatx4 acc[4][8];
#pragma unroll
  for (int i = 0; i < 4; ++i)
#pragma unroll
    for (int j = 0; j < 8; ++j) acc[i][j] = (floatx4)(0.0f);

  // q prefetch: 2 steps in flight, both n-halves
  uintx4 q0a = *(const uintx4*)qptr;
  uintx4 q0b = *(const uintx4*)(qptr + 64);
  qptr += 4 * (size_t)N_DIM;
  uintx4 q1a = q0a, q1b = q0b;
  if (STEPS > 1) {
    q1a = *(const uintx4*)qptr;
    q1b = *(const uintx4*)(qptr + 64);
  }
  qptr += 4 * (size_t)N_DIM;
  floatx4 scv0 = *(const floatx4*)sptr;
  floatx4 scv1 = *(const floatx4*)(sptr + 64);
  sptr += N_DIM;

  for (int g = 0; g < GROUPS; ++g) {
    uint32_t s2b[8];
#pragma unroll
    for (int d = 0; d < 4; ++d) {
      unsigned short sb = bc<unsigned short>((_Float16)scv0[d]);  // exact
      uint32_t u = (uint32_t)sb;
      s2b[d] = u | (u << 16);  // fp16x2 splat
      unsigned short sb1 = bc<unsigned short>((_Float16)scv1[d]);
      uint32_t u1 = (uint32_t)sb1;
      s2b[4 + d] = u1 | (u1 << 16);
    }
    floatx4 scn0 = scv0, scn1 = scv1;
    if (g + 1 < GROUPS) {
      scn0 = *(const floatx4*)sptr;
      scn1 = *(const floatx4*)(sptr + 64);
    }
    sptr += N_DIM;
#pragma unroll
    for (int tt = 0; tt < 4; ++tt) {
      const int t = g * 4 + tt;
      // A fragments for THIS step (L1/L2-resident Apack; 4 x dwordx4),
      // reused across both n-halves (8 dequant columns).
      halfx8 afr[4];
      if constexpr (PACKED) {
#pragma unroll
        for (int mf = 0; mf < 4; ++mf)
          afr[mf] = *(const halfx8*)(apt + mf * 512);
        apt += 2048;
      } else {
#pragma unroll
        for (int mf = 0; mf < 4; ++mf) {
          const float* s0 = araw + (size_t)mf * 16 * K_DIM + (size_t)t * 32;
          floatx4 a0 = *(const floatx4*)s0;
          floatx4 a1 = *(const floatx4*)(s0 + 4);
          afr[mf][0] = (_Float16)a0[0]; afr[mf][1] = (_Float16)a1[0];
          afr[mf][2] = (_Float16)a0[1]; afr[mf][3] = (_Float16)a1[1];
          afr[mf][4] = (_Float16)a0[2]; afr[mf][5] = (_Float16)a1[2];
          afr[mf][6] = (_Float16)a0[3]; afr[mf][7] = (_Float16)a1[3];
        }
      }
      // q prefetch for step t+2 (issued AFTER A so the A-wait keeps them
      // in flight under in-order vmcnt)
      uintx4 qna = q1a, qnb = q1b;
      if (t + 2 < STEPS) {
        qna = *(const uintx4*)qptr;
        qnb = *(const uintx4*)(qptr + 64);
      }
      qptr += 4 * (size_t)N_DIM;

      // half 0 then half 1; d-major keeps B's live range short
#pragma unroll
      for (int d = 0; d < 4; ++d) {
        halfx8 b = dequant8(q0a[d], s2b[d]);
#pragma unroll
        for (int mf = 0; mf < 4; ++mf)
          acc[mf][d] = __builtin_amdgcn_mfma_f32_16x16x32_f16(afr[mf], b,
                                                              acc[mf][d], 0, 0, 0);
      }
#pragma unroll
      for (int d = 0; d < 4; ++d) {
        halfx8 b = dequant8(q0b[d], s2b[4 + d]);
#pragma unroll
        for (int mf = 0; mf < 4; ++mf)
          acc[mf][4 + d] = __builtin_amdgcn_mfma_f32_16x16x32_f16(afr[mf], b,
                                                                  acc[mf][4 + d], 0, 0, 0);
      }
      q0a = q1a; q0b = q1b;
      q1a = qna; q1b = qnb;
    }
    scv0 = scn0;
    scv1 = scn1;
  }

  // Epilogue. C layout: row = 4*l4 + reg (+16*mf), col = l&15; fragment d's
  // col c is global n = nh + 4*c + d (nh = nb + 64*h) -> 4 fragments at
  // fixed (mf, r, h) are 4 consecutive n. Output is FP32.
  if (SPLIT) {
    float* pbase = part + (size_t)blockIdx.y * ((size_t)M_DIM * N_DIM);
#pragma unroll
    for (int h = 0; h < 2; ++h) {
      const int nc = ncol + 64 * h;
#pragma unroll
      for (int mf = 0; mf < 4; ++mf) {
#pragma unroll
        for (int r = 0; r < 4; ++r) {
          const int m = mf * 16 + l4 * 4 + r;
          floatx4 v = {acc[mf][4 * h + 0][r], acc[mf][4 * h + 1][r],
                       acc[mf][4 * h + 2][r], acc[mf][4 * h + 3][r]};
          *(floatx4*)(pbase + (size_t)m * N_DIM + nc) = v;
        }
      }
    }
  } else {
#pragma unroll
    for (int h = 0; h < 2; ++h) {
      const int nc = ncol + 64 * h;
      floatx4 bb = *(const floatx4*)(bias + nc);
#pragma unroll
      for (int mf = 0; mf < 4; ++mf) {
#pragma unroll
        for (int r = 0; r < 4; ++r) {
          const int m = mf * 16 + l4 * 4 + r;
          floatx4 v = {acc[mf][4 * h + 0][r] + bb.x, acc[mf][4 * h + 1][r] + bb.y,
                       acc[mf][4 * h + 2][r] + bb.z, acc[mf][4 * h + 3][r] + bb.w};
          *(floatx4*)(out + (size_t)m * N_DIM + nc) = v;
        }
      }
    }
  }
}

// Sum KS fp32 partials, add fp32 bias, emit fp32.
template <int KS>
__global__ __launch_bounds__(256) void wq_reduce(const float* __restrict__ part,
                                                 const float* __restrict__ bias,
                                                 float* __restrict__ out) {
  const int idx = (int)blockIdx.x * 256 + (int)threadIdx.x;  // over M*N/4
  const int m = idx / (N_DIM / 4);
  const int n = (idx - m * (N_DIM / 4)) * 4;
  floatx4 s = (floatx4)(0.0f);
#pragma unroll
  for (int p = 0; p < KS; ++p)
    s += *(const floatx4*)(part + ((size_t)p * M_DIM + m) * N_DIM + n);
  floatx4 bb = *(const floatx4*)(bias + n);
  s += bb;
  *(floatx4*)(out + (size_t)m * N_DIM + n) = s;
}

extern "C" void kernel_launch(void* const* d_in, const int* in_sizes, int n_in,
                              void* d_out, int out_size, void* d_ws, size_t ws_size,
                              hipStream_t stream) {
  const float* A = (const float*)d_in[0];    // fp32 (64x8192), fp16-exact
  const int* qw = (const int*)d_in[1];       // int32 (1024x28672)
  const float* sc = (const float*)d_in[2];   // fp32 (64x28672), fp16-exact
  const float* bi = (const float*)d_in[3];   // fp32 (28672), fp16-exact
  float* out = (float*)d_out;                // fp32 (64x28672)

  char* ws = (char*)d_ws;
  const size_t packB = (size_t)M_DIM * K_DIM * sizeof(_Float16);  // 1 MiB
  const size_t mnB = (size_t)M_DIM * N_DIM * sizeof(float);       // 7.34 MB
  _Float16* Apack = (_Float16*)ws;
  float* part = (float*)(ws + packB);

  const int nblk = N_DIM / 128;                // 224 (1-wave 128n blocks)
  const int rblk = (M_DIM * N_DIM / 4) / 256;  // 1792

  if (ws_size >= packB + 2 * mnB) {
    pack_a<<<256, 256, 0, stream>>>(A, Apack);
    wq_mfma<K_DIM / 2, true, true><<<dim3(nblk, 2), 64, 0, stream>>>(
        A, Apack, qw, sc, bi, part, out);
    wq_reduce<2><<<rblk, 256, 0, stream>>>(part, bi, out);
  } else if (ws_size >= packB) {
    pack_a<<<256, 256, 0, stream>>>(A, Apack);
    wq_mfma<K_DIM, false, true><<<dim3(nblk, 1), 64, 0, stream>>>(
        A, Apack, qw, sc, bi, part, out);
  } else {
    wq_mfma<K_DIM, false, false><<<dim3(nblk, 1), 64, 0, stream>>>(
        A, (const _Float16*)nullptr, qw, sc, bi, part, out);
  }
}

// Round 5
// 215.128 us; speedup vs baseline: 1.3723x; 1.3723x over previous
//
#include <hip/hip_runtime.h>
#include <hip/hip_fp16.h>
#include <stdint.h>

#define M_DIM 64
#define K_DIM 8192
#define N_DIM 28672
#define QGROUP 128

typedef __attribute__((ext_vector_type(4))) float floatx4;
typedef __attribute__((ext_vector_type(8))) _Float16 halfx8;
typedef __attribute__((ext_vector_type(4))) uint32_t uintx4;

// bit_cast via memcpy (works for non-trivially-copyable HIP types)
template <typename T, typename F>
__device__ __forceinline__ T bc(F f) {
  static_assert(sizeof(T) == sizeof(F), "size mismatch");
  T t;
  __builtin_memcpy(&t, &f, sizeof(T));
  return t;
}

// p = two fp16 lanes holding (1024+nib); returns two fp16 of (nib-8)*s
// (1024+nib and 1032 are fp16-exact, same binade -> sub exact; mul RNE =
// exactly the reference's fp16 multiply)
__device__ __forceinline__ uint32_t dq_pair(uint32_t p, uint32_t s2bits) {
  __half2 v = bc<__half2>(p);
  __half2 z = bc<__half2>(0x64086408u);  // (1032, 1032)
  __half2 s = bc<__half2>(s2bits);
  return bc<uint32_t>(__hmul2(__hsub2(v, z), s));
}

// one packed dword (8 nibbles) -> B fragment (8 fp16) for one n, in the
// PERMUTED k-order [0,4,1,5,2,6,3,7]: pair j extracts nibbles (j, j+4) with
// one shift + one v_and_or_b32. Apack uses the same k-order, so the MFMA
// contraction is consistent.
__device__ __forceinline__ halfx8 dequant8(uint32_t q, uint32_t s2bits) {
  const uint32_t MM = 0x000F000Fu;
  const uint32_t MG = 0x64006400u;  // fp16(1024) in both halves
  uintx4 r;
  r.x = dq_pair((q & MM) | MG, s2bits);          // k0 | k4
  r.y = dq_pair(((q >> 4) & MM) | MG, s2bits);   // k1 | k5
  r.z = dq_pair(((q >> 8) & MM) | MG, s2bits);   // k2 | k6
  r.w = dq_pair(((q >> 12) & MM) | MG, s2bits);  // k3 | k7
  return bc<halfx8>(r);
}

// A (fp32, 64x8192, fp16-exact) -> fragment-ordered fp16 pack, with the
// SAME within-8 k-permutation [0,4,1,5,2,6,3,7] as dequant8.
// Apack[((t*4+mf)*64 + l)*8 + j] =
//   (f16) A[(l&15)+16*mf][32*t + 8*(l>>4) + perm[j]]
__global__ __launch_bounds__(256) void pack_a(const float* __restrict__ A,
                                              _Float16* __restrict__ Apack) {
  const int g = (int)blockIdx.x * 256 + (int)threadIdx.x;  // 0 .. 65535
  const int l = g & 63;
  const int mf = (g >> 6) & 3;
  const int t = g >> 8;
  const int row = (l & 15) + 16 * mf;
  const int k0 = 32 * t + 8 * (l >> 4);
  const float* src = A + (size_t)row * K_DIM + k0;
  floatx4 a0 = *(const floatx4*)src;        // k 0..3
  floatx4 a1 = *(const floatx4*)(src + 4);  // k 4..7
  halfx8 hv;
  hv[0] = (_Float16)a0[0]; hv[1] = (_Float16)a1[0];
  hv[2] = (_Float16)a0[1]; hv[3] = (_Float16)a1[1];
  hv[4] = (_Float16)a0[2]; hv[5] = (_Float16)a1[2];
  hv[6] = (_Float16)a0[3]; hv[7] = (_Float16)a1[3];
  *(halfx8*)(Apack + (size_t)g * 8) = hv;
}

// ONE WAVE PER BLOCK (64 threads), wave tile 64m x 128n.
// Occupancy law from rounds 0-4: per-CU throughput peaks at ~7 waves/CU
// (r0/r2: 445-469 cyc/unit; 14/CU: 482-536; 1.75/CU: 852). So grid
// (224, 8) = 1792 waves = exactly 7/CU.
// Pipeline law (in-order vmcnt): the s_waitcnt for this step's A drains
// every OLDER load. r2 issued+waited A in the same step -> A L2 latency
// fully exposed + q window collapsed to 1 step. Here A is prefetched 1
// step ahead and issued BEFORE the step's q loads, so the wait at step t
// (for A_t, issued t-1) leaves the newer q's in flight: A hidden, q gets
// 2 full steps. launch_bounds(64,2) -> 256-reg budget for the pipeline.
template <int KSLICE, bool SPLIT, bool PACKED>
__global__ __launch_bounds__(64, 2) void wq_mfma(
    const float* __restrict__ A,        // fp32 raw (only used if !PACKED)
    const _Float16* __restrict__ Apack, // fragment-ordered fp16
    const int* __restrict__ qweight,    // int32, K/8 x N
    const float* __restrict__ scales,   // fp32, K/128 x N (fp16-exact)
    const float* __restrict__ bias,     // fp32, N (fp16-exact)
    float* __restrict__ part,           // KSPLIT x M x N (fp32)
    float* __restrict__ out) {          // fp32, M x N
  constexpr int STEPS = KSLICE / 32;
  constexpr int GROUPS = KSLICE / QGROUP;

  const int l = (int)threadIdx.x & 63;
  const int l15 = l & 15;
  const int l4 = l >> 4;
  const int nb = (int)blockIdx.x * 128;
  const int kb = (int)blockIdx.y * KSLICE;
  const int ncol = nb + 4 * l15;  // lane's first n in half 0; half 1 at +64

  const int* qptr = qweight + (size_t)((kb >> 3) + l4) * N_DIM + ncol;
  const float* sptr = scales + (size_t)(kb / QGROUP) * N_DIM + ncol;
  // per-step stride 2048 halves (4 KB); mf at +512 halves (imm offset)
  const _Float16* apt = Apack + ((size_t)(kb >> 5) * 256 + l) * 8;
  // raw-A fallback base (row l15, k = kb + 8*l4); mf at +16 rows
  const float* araw = A + (size_t)l15 * K_DIM + (kb + 8 * l4);

  floatx4 acc[4][8];
#pragma unroll
  for (int i = 0; i < 4; ++i)
#pragma unroll
    for (int j = 0; j < 8; ++j) acc[i][j] = (floatx4)(0.0f);

  // ---- prologue: q for steps 0,1; scales; A for step 0 (issued LAST so
  // its wait does not early-drain the q stream beyond what's needed) ----
  uintx4 q0a = *(const uintx4*)qptr;
  uintx4 q0b = *(const uintx4*)(qptr + 64);
  qptr += 4 * (size_t)N_DIM;
  uintx4 q1a = q0a, q1b = q0b;
  if (STEPS > 1) {
    q1a = *(const uintx4*)qptr;
    q1b = *(const uintx4*)(qptr + 64);
  }
  qptr += 4 * (size_t)N_DIM;
  floatx4 scv0 = *(const floatx4*)sptr;
  floatx4 scv1 = *(const floatx4*)(sptr + 64);
  sptr += N_DIM;

  halfx8 afr[2][4];  // double-buffered A fragments (parity = step & 1)
  if constexpr (PACKED) {
#pragma unroll
    for (int mf = 0; mf < 4; ++mf) afr[0][mf] = *(const halfx8*)(apt + mf * 512);
    apt += 2048;
  } else {
#pragma unroll
    for (int mf = 0; mf < 4; ++mf) {
      const float* s0 = araw + (size_t)mf * 16 * K_DIM;
      floatx4 a0 = *(const floatx4*)s0;
      floatx4 a1 = *(const floatx4*)(s0 + 4);
      afr[0][mf][0] = (_Float16)a0[0]; afr[0][mf][1] = (_Float16)a1[0];
      afr[0][mf][2] = (_Float16)a0[1]; afr[0][mf][3] = (_Float16)a1[1];
      afr[0][mf][4] = (_Float16)a0[2]; afr[0][mf][5] = (_Float16)a1[2];
      afr[0][mf][6] = (_Float16)a0[3]; afr[0][mf][7] = (_Float16)a1[3];
    }
  }

  for (int g = 0; g < GROUPS; ++g) {
    uint32_t s2b[8];
#pragma unroll
    for (int d = 0; d < 4; ++d) {
      unsigned short sb = bc<unsigned short>((_Float16)scv0[d]);  // exact
      uint32_t u = (uint32_t)sb;
      s2b[d] = u | (u << 16);  // fp16x2 splat
      unsigned short sb1 = bc<unsigned short>((_Float16)scv1[d]);
      uint32_t u1 = (uint32_t)sb1;
      s2b[4 + d] = u1 | (u1 << 16);
    }
    floatx4 scn0 = scv0, scn1 = scv1;
    if (g + 1 < GROUPS) {
      scn0 = *(const floatx4*)sptr;
      scn1 = *(const floatx4*)(sptr + 64);
    }
    sptr += N_DIM;
#pragma unroll
    for (int tt = 0; tt < 4; ++tt) {
      const int t = g * 4 + tt;
      const int p = tt & 1;         // t&1: g*4 is even
      const int pn = (tt + 1) & 1;
      // 1) A prefetch for step t+1 — issued FIRST so the wait on afr[p]
      //    (A_t, issued last step) leaves these and the q's in flight.
      if constexpr (PACKED) {
        if (t + 1 < STEPS) {
#pragma unroll
          for (int mf = 0; mf < 4; ++mf)
            afr[pn][mf] = *(const halfx8*)(apt + mf * 512);
        }
        apt += 2048;
      } else {
        if (t + 1 < STEPS) {
#pragma unroll
          for (int mf = 0; mf < 4; ++mf) {
            const float* s0 = araw + (size_t)mf * 16 * K_DIM + (size_t)(t + 1) * 32;
            floatx4 a0 = *(const floatx4*)s0;
            floatx4 a1 = *(const floatx4*)(s0 + 4);
            afr[pn][mf][0] = (_Float16)a0[0]; afr[pn][mf][1] = (_Float16)a1[0];
            afr[pn][mf][2] = (_Float16)a0[1]; afr[pn][mf][3] = (_Float16)a1[1];
            afr[pn][mf][4] = (_Float16)a0[2]; afr[pn][mf][5] = (_Float16)a1[2];
            afr[pn][mf][6] = (_Float16)a0[3]; afr[pn][mf][7] = (_Float16)a1[3];
          }
        }
      }
      // 2) q prefetch for step t+2 (newer than A_{t+1} -> survives its wait;
      //    force-drained only at step t+2's wait = 2 full steps of cover)
      uintx4 qna = q1a, qnb = q1b;
      if (t + 2 < STEPS) {
        qna = *(const uintx4*)qptr;
        qnb = *(const uintx4*)(qptr + 64);
      }
      qptr += 4 * (size_t)N_DIM;

      // 3) compute: half 0 then half 1; d-major keeps B's live range short
#pragma unroll
      for (int d = 0; d < 4; ++d) {
        halfx8 b = dequant8(q0a[d], s2b[d]);
#pragma unroll
        for (int mf = 0; mf < 4; ++mf)
          acc[mf][d] = __builtin_amdgcn_mfma_f32_16x16x32_f16(afr[p][mf], b,
                                                              acc[mf][d], 0, 0, 0);
      }
#pragma unroll
      for (int d = 0; d < 4; ++d) {
        halfx8 b = dequant8(q0b[d], s2b[4 + d]);
#pragma unroll
        for (int mf = 0; mf < 4; ++mf)
          acc[mf][4 + d] = __builtin_amdgcn_mfma_f32_16x16x32_f16(afr[p][mf], b,
                                                                  acc[mf][4 + d], 0, 0, 0);
      }
      q0a = q1a; q0b = q1b;
      q1a = qna; q1b = qnb;
    }
    scv0 = scn0;
    scv1 = scn1;
  }

  // Epilogue. C layout: row = 4*l4 + reg (+16*mf), col = l&15; fragment d's
  // col c is global n = nh + 4*c + d (nh = nb + 64*h) -> 4 fragments at
  // fixed (mf, r, h) are 4 consecutive n. Output is FP32.
  if (SPLIT) {
    float* pbase = part + (size_t)blockIdx.y * ((size_t)M_DIM * N_DIM);
#pragma unroll
    for (int h = 0; h < 2; ++h) {
      const int nc = ncol + 64 * h;
#pragma unroll
      for (int mf = 0; mf < 4; ++mf) {
#pragma unroll
        for (int r = 0; r < 4; ++r) {
          const int m = mf * 16 + l4 * 4 + r;
          floatx4 v = {acc[mf][4 * h + 0][r], acc[mf][4 * h + 1][r],
                       acc[mf][4 * h + 2][r], acc[mf][4 * h + 3][r]};
          *(floatx4*)(pbase + (size_t)m * N_DIM + nc) = v;
        }
      }
    }
  } else {
#pragma unroll
    for (int h = 0; h < 2; ++h) {
      const int nc = ncol + 64 * h;
      floatx4 bb = *(const floatx4*)(bias + nc);
#pragma unroll
      for (int mf = 0; mf < 4; ++mf) {
#pragma unroll
        for (int r = 0; r < 4; ++r) {
          const int m = mf * 16 + l4 * 4 + r;
          floatx4 v = {acc[mf][4 * h + 0][r] + bb.x, acc[mf][4 * h + 1][r] + bb.y,
                       acc[mf][4 * h + 2][r] + bb.z, acc[mf][4 * h + 3][r] + bb.w};
          *(floatx4*)(out + (size_t)m * N_DIM + nc) = v;
        }
      }
    }
  }
}

// Sum KS fp32 partials, add fp32 bias, emit fp32.
template <int KS>
__global__ __launch_bounds__(256) void wq_reduce(const float* __restrict__ part,
                                                 const float* __restrict__ bias,
                                                 float* __restrict__ out) {
  const int idx = (int)blockIdx.x * 256 + (int)threadIdx.x;  // over M*N/4
  const int m = idx / (N_DIM / 4);
  const int n = (idx - m * (N_DIM / 4)) * 4;
  floatx4 s = (floatx4)(0.0f);
#pragma unroll
  for (int p = 0; p < KS; ++p)
    s += *(const floatx4*)(part + ((size_t)p * M_DIM + m) * N_DIM + n);
  floatx4 bb = *(const floatx4*)(bias + n);
  s += bb;
  *(floatx4*)(out + (size_t)m * N_DIM + n) = s;
}

extern "C" void kernel_launch(void* const* d_in, const int* in_sizes, int n_in,
                              void* d_out, int out_size, void* d_ws, size_t ws_size,
                              hipStream_t stream) {
  const float* A = (const float*)d_in[0];    // fp32 (64x8192), fp16-exact
  const int* qw = (const int*)d_in[1];       // int32 (1024x28672)
  const float* sc = (const float*)d_in[2];   // fp32 (64x28672), fp16-exact
  const float* bi = (const float*)d_in[3];   // fp32 (28672), fp16-exact
  float* out = (float*)d_out;                // fp32 (64x28672)

  char* ws = (char*)d_ws;
  const size_t packB = (size_t)M_DIM * K_DIM * sizeof(_Float16);  // 1 MiB
  const size_t mnB = (size_t)M_DIM * N_DIM * sizeof(float);       // 7.34 MB
  _Float16* Apack = (_Float16*)ws;
  float* part = (float*)(ws + packB);

  const int nblk = N_DIM / 128;                // 224 (1-wave 128n blocks)
  const int rblk = (M_DIM * N_DIM / 4) / 256;  // 1792

  if (ws_size >= packB + 8 * mnB) {
    // 224 x 8 = 1792 waves = 7 waves/CU (measured optimum)
    pack_a<<<256, 256, 0, stream>>>(A, Apack);
    wq_mfma<K_DIM / 8, true, true><<<dim3(nblk, 8), 64, 0, stream>>>(
        A, Apack, qw, sc, bi, part, out);
    wq_reduce<8><<<rblk, 256, 0, stream>>>(part, bi, out);
  } else if (ws_size >= packB + 4 * mnB) {
    pack_a<<<256, 256, 0, stream>>>(A, Apack);
    wq_mfma<K_DIM / 4, true, true><<<dim3(nblk, 4), 64, 0, stream>>>(
        A, Apack, qw, sc, bi, part, out);
    wq_reduce<4><<<rblk, 256, 0, stream>>>(part, bi, out);
  } else if (ws_size >= packB + 2 * mnB) {
    pack_a<<<256, 256, 0, stream>>>(A, Apack);
    wq_mfma<K_DIM / 2, true, true><<<dim3(nblk, 2), 64, 0, stream>>>(
        A, Apack, qw, sc, bi, part, out);
    wq_reduce<2><<<rblk, 256, 0, stream>>>(part, bi, out);
  } else if (ws_size >= packB) {
    pack_a<<<256, 256, 0, stream>>>(A, Apack);
    wq_mfma<K_DIM, false, true><<<dim3(nblk, 1), 64, 0, stream>>>(
        A, Apack, qw, sc, bi, part, out);
  } else {
    wq_mfma<K_DIM, false, false><<<dim3(nblk, 1), 64, 0, stream>>>(
        A, (const _Float16*)nullptr, qw, sc, bi, part, out);
  }
}

// Round 6
// 203.827 us; speedup vs baseline: 1.4484x; 1.0554x over previous
//
#include <hip/hip_runtime.h>
#include <hip/hip_fp16.h>
#include <stdint.h>

#define M_DIM 64
#define K_DIM 8192
#define N_DIM 28672
#define QGROUP 128

typedef __attribute__((ext_vector_type(4))) float floatx4;
typedef __attribute__((ext_vector_type(8))) _Float16 halfx8;
typedef __attribute__((ext_vector_type(4))) uint32_t uintx4;

template <typename T, typename F>
__device__ __forceinline__ T bc(F f) {
  static_assert(sizeof(T) == sizeof(F), "size mismatch");
  T t;
  __builtin_memcpy(&t, &f, sizeof(T));
  return t;
}

// p = two fp16 lanes holding (1024+nib); returns two fp16 of (nib-8)*s
__device__ __forceinline__ uint32_t dq_pair(uint32_t p, uint32_t s2bits) {
  __half2 v = bc<__half2>(p);
  __half2 z = bc<__half2>(0x64086408u);  // (1032, 1032)
  __half2 s = bc<__half2>(s2bits);
  return bc<uint32_t>(__hmul2(__hsub2(v, z), s));
}

// one packed dword -> 8 fp16 in PERMUTED k-order [0,4,1,5,2,6,3,7]
__device__ __forceinline__ halfx8 dequant8(uint32_t q, uint32_t s2bits) {
  const uint32_t MM = 0x000F000Fu;
  const uint32_t MG = 0x64006400u;
  uintx4 r;
  r.x = dq_pair((q & MM) | MG, s2bits);
  r.y = dq_pair(((q >> 4) & MM) | MG, s2bits);
  r.z = dq_pair(((q >> 8) & MM) | MG, s2bits);
  r.w = dq_pair(((q >> 12) & MM) | MG, s2bits);
  return bc<halfx8>(r);
}

// A (fp32) -> fragment-ordered fp16 pack with the same k-permutation.
// Apack[((t*4+mf)*64 + l)*8 + j] = (f16)A[(l&15)+16*mf][32*t + 8*(l>>4) + perm[j]]
__global__ __launch_bounds__(256) void pack_a(const float* __restrict__ A,
                                              _Float16* __restrict__ Apack) {
  const int g = (int)blockIdx.x * 256 + (int)threadIdx.x;
  const int l = g & 63;
  const int mf = (g >> 6) & 3;
  const int t = g >> 8;
  const int row = (l & 15) + 16 * mf;
  const int k0 = 32 * t + 8 * (l >> 4);
  const float* src = A + (size_t)row * K_DIM + k0;
  floatx4 a0 = *(const floatx4*)src;
  floatx4 a1 = *(const floatx4*)(src + 4);
  halfx8 hv;
  hv[0] = (_Float16)a0[0]; hv[1] = (_Float16)a1[0];
  hv[2] = (_Float16)a0[1]; hv[3] = (_Float16)a1[1];
  hv[4] = (_Float16)a0[2]; hv[5] = (_Float16)a1[2];
  hv[6] = (_Float16)a0[3]; hv[7] = (_Float16)a1[3];
  *(halfx8*)(Apack + (size_t)g * 8) = hv;
}

// global -> LDS DMA, 16B per lane; lds base must be wave-uniform.
__device__ __forceinline__ void stage16(const _Float16* gsrc, _Float16* lds) {
  __builtin_amdgcn_global_load_lds(
      (const __attribute__((address_space(1))) uint32_t*)gsrc,
      (__attribute__((address_space(3))) uint32_t*)lds, 16, 0, 0);
}

// 4-wave block (256 thr), block tile 64m x 512n, per-wave 64m x 128n.
// A staged per block per 32-K step (4 KB) via global_load_lds into a 4-deep
// LDS ring, 2 steps ahead; q prefetched 4 steps deep in compile-time slots.
// Counted vmcnt(3) + raw s_barrier per step: future loads NEVER drained
// (the r0-r5 kernels force-retired the whole vmem queue every step -> ~2KB
// in flight -> 1.6 TB/s delivery; this keeps 3-4KB+/wave in flight).
// Grid (56, KSPLIT): KSPLIT=8 -> 448 blocks = 7 waves/CU (measured optimum).
template <int KSLICE, bool SPLIT>
__global__ __launch_bounds__(256, 2) void wq_lds(
    const _Float16* __restrict__ Apack, // fragment-ordered fp16
    const int* __restrict__ qweight,    // int32, K/8 x N
    const float* __restrict__ scales,   // fp32, K/128 x N (fp16-exact)
    const float* __restrict__ bias,     // fp32, N (fp16-exact)
    float* __restrict__ part,           // KSPLIT x M x N (fp32)
    float* __restrict__ out) {          // fp32, M x N
  constexpr int STEPS = KSLICE / 32;    // >= 32 for all tiers
  constexpr int GROUPS = KSLICE / QGROUP;
  __shared__ __align__(16) _Float16 Abuf[4][2048];  // 4 x 4KB ring

  const int tid = (int)threadIdx.x;
  const int w = tid >> 6;
  const int l = tid & 63;
  const int l15 = l & 15;
  const int l4 = l >> 4;
  const int nbW = (int)blockIdx.x * 512 + w * 128;
  const int kb = (int)blockIdx.y * KSLICE;
  const int ncol = nbW + 4 * l15;

  const int* qptr = qweight + (size_t)((kb >> 3) + l4) * N_DIM + ncol;
  const float* sptr = scales + (size_t)(kb / QGROUP) * N_DIM + ncol;
  const _Float16* asrc = Apack + (size_t)(kb >> 5) * 2048 + tid * 8;
  _Float16* const ldsw = &Abuf[0][0] + w * 512;  // wave's quarter (uniform)

  floatx4 acc[4][8];
#pragma unroll
  for (int i = 0; i < 4; ++i)
#pragma unroll
    for (int j = 0; j < 8; ++j) acc[i][j] = (floatx4)(0.0f);

  // ---- prologue: q_0..q_3 (slots 0..3), scales g0, stage steps 0,1; then
  // ONE full drain + barrier establishes clean vmcnt cadence ----
  uintx4 qa[4], qb[4];
#pragma unroll
  for (int s = 0; s < 4; ++s) {
    qa[s] = *(const uintx4*)qptr;
    qb[s] = *(const uintx4*)(qptr + 64);
    qptr += 4 * (size_t)N_DIM;  // -> step s+1 rows; ends at step 4
  }
  floatx4 scv0 = *(const floatx4*)sptr;
  floatx4 scv1 = *(const floatx4*)(sptr + 64);
  sptr += N_DIM;
  stage16(asrc, ldsw);          // step 0 -> buf0
  asrc += 2048;
  stage16(asrc, ldsw + 2048);   // step 1 -> buf1
  asrc += 2048;
  __syncthreads();              // vmcnt(0)+lgkmcnt(0)+barrier, once

  floatx4 scn0 = scv0, scn1 = scv1;

  for (int g = 0; g < GROUPS; ++g) {
    uint32_t s2b[8];
#pragma unroll
    for (int d = 0; d < 4; ++d) {
      unsigned short sb0 = bc<unsigned short>((_Float16)scv0[d]);
      uint32_t u0 = (uint32_t)sb0;
      s2b[d] = u0 | (u0 << 16);
      unsigned short sb1 = bc<unsigned short>((_Float16)scv1[d]);
      uint32_t u1 = (uint32_t)sb1;
      s2b[4 + d] = u1 | (u1 << 16);
    }
#pragma unroll
    for (int tt = 0; tt < 4; ++tt) {
      const int t = g * 4 + tt;  // buf index = t&3 = tt (compile-time)
      // Counted wait: retire stage_t (issued 2 iters ago; >=3 newer vmem
      // ops follow it by pinned order) WITHOUT draining q_{t+1..t+3} /
      // stage_{t+1}. Then barrier: all waves' stage_t parts landed.
      asm volatile("s_waitcnt vmcnt(3)" ::: "memory");
      __builtin_amdgcn_s_barrier();
      __builtin_amdgcn_sched_barrier(0);
      // A fragments: conflict-free ds_read_b128 (lanes consecutive 16B)
      halfx8 afr[4];
#pragma unroll
      for (int mf = 0; mf < 4; ++mf)
        afr[mf] = *(const halfx8*)&Abuf[tt][mf * 512 + l * 8];
      // compute: 8 dequant columns x 4 m-fragments = 32 MFMA
#pragma unroll
      for (int d = 0; d < 4; ++d) {
        halfx8 b = dequant8(qa[tt][d], s2b[d]);
#pragma unroll
        for (int mf = 0; mf < 4; ++mf)
          acc[mf][d] = __builtin_amdgcn_mfma_f32_16x16x32_f16(afr[mf], b,
                                                              acc[mf][d], 0, 0, 0);
      }
#pragma unroll
      for (int d = 0; d < 4; ++d) {
        halfx8 b = dequant8(qb[tt][d], s2b[4 + d]);
#pragma unroll
        for (int mf = 0; mf < 4; ++mf)
          acc[mf][4 + d] = __builtin_amdgcn_mfma_f32_16x16x32_f16(afr[mf], b,
                                                                  acc[mf][4 + d], 0, 0, 0);
      }
      __builtin_amdgcn_sched_barrier(0);
      // stage step t+2 into buf[(tt+2)&3] (clamped address at the tail so
      // the vmcnt cadence stays exact; stale stages are never read)
      stage16(asrc, ldsw + ((tt + 2) & 3) * 2048);
      asrc += (t + 3 < STEPS) ? 2048 : 0;
      __builtin_amdgcn_sched_barrier(0);  // pin: stage before q
      // q for step t+4 into slot tt (consumed above -> no WAR copies)
      qa[tt] = *(const uintx4*)qptr;
      qb[tt] = *(const uintx4*)(qptr + 64);
      qptr += (t + 5 < STEPS) ? 4 * (size_t)N_DIM : (size_t)0;
      if (tt == 0) {  // scales for group g+1 (3-iter cover, clamped)
        scn0 = *(const floatx4*)sptr;
        scn1 = *(const floatx4*)(sptr + 64);
        sptr += (g + 1 < GROUPS) ? N_DIM : 0;
      }
      __builtin_amdgcn_sched_barrier(0);
    }
    scv0 = scn0;
    scv1 = scn1;
  }

  // Epilogue. row = 4*l4 + r (+16*mf), col = l&15; fragment d at (mf,r,h)
  // covers n = nbW + 64*h + 4*(l&15) + d -> 4 consecutive n.
  if (SPLIT) {
    float* pbase = part + (size_t)blockIdx.y * ((size_t)M_DIM * N_DIM);
#pragma unroll
    for (int h = 0; h < 2; ++h) {
      const int nc = ncol + 64 * h;
#pragma unroll
      for (int mf = 0; mf < 4; ++mf) {
#pragma unroll
        for (int r = 0; r < 4; ++r) {
          const int m = mf * 16 + l4 * 4 + r;
          floatx4 v = {acc[mf][4 * h + 0][r], acc[mf][4 * h + 1][r],
                       acc[mf][4 * h + 2][r], acc[mf][4 * h + 3][r]};
          *(floatx4*)(pbase + (size_t)m * N_DIM + nc) = v;
        }
      }
    }
  } else {
#pragma unroll
    for (int h = 0; h < 2; ++h) {
      const int nc = ncol + 64 * h;
      floatx4 bb = *(const floatx4*)(bias + nc);
#pragma unroll
      for (int mf = 0; mf < 4; ++mf) {
#pragma unroll
        for (int r = 0; r < 4; ++r) {
          const int m = mf * 16 + l4 * 4 + r;
          floatx4 v = {acc[mf][4 * h + 0][r] + bb.x, acc[mf][4 * h + 1][r] + bb.y,
                       acc[mf][4 * h + 2][r] + bb.z, acc[mf][4 * h + 3][r] + bb.w};
          *(floatx4*)(out + (size_t)m * N_DIM + nc) = v;
        }
      }
    }
  }
}

// Fallback (no workspace): r5's register kernel, raw fp32 A, full K, 1 wave.
__global__ __launch_bounds__(64, 2) void wq_reg(
    const float* __restrict__ A, const int* __restrict__ qweight,
    const float* __restrict__ scales, const float* __restrict__ bias,
    float* __restrict__ out) {
  constexpr int KSLICE = K_DIM;
  constexpr int STEPS = KSLICE / 32;
  constexpr int GROUPS = KSLICE / QGROUP;
  const int l = (int)threadIdx.x & 63;
  const int l15 = l & 15;
  const int l4 = l >> 4;
  const int nb = (int)blockIdx.x * 128;
  const int ncol = nb + 4 * l15;
  const int* qptr = qweight + (size_t)l4 * N_DIM + ncol;
  const float* sptr = scales + ncol;
  const float* araw = A + (size_t)l15 * K_DIM + 8 * l4;

  floatx4 acc[4][8];
#pragma unroll
  for (int i = 0; i < 4; ++i)
#pragma unroll
    for (int j = 0; j < 8; ++j) acc[i][j] = (floatx4)(0.0f);

  uintx4 q0a = *(const uintx4*)qptr;
  uintx4 q0b = *(const uintx4*)(qptr + 64);
  qptr += 4 * (size_t)N_DIM;
  uintx4 q1a = *(const uintx4*)qptr;
  uintx4 q1b = *(const uintx4*)(qptr + 64);
  qptr += 4 * (size_t)N_DIM;
  floatx4 scv0 = *(const floatx4*)sptr;
  floatx4 scv1 = *(const floatx4*)(sptr + 64);
  sptr += N_DIM;

  for (int g = 0; g < GROUPS; ++g) {
    uint32_t s2b[8];
#pragma unroll
    for (int d = 0; d < 4; ++d) {
      unsigned short sb0 = bc<unsigned short>((_Float16)scv0[d]);
      uint32_t u0 = (uint32_t)sb0;
      s2b[d] = u0 | (u0 << 16);
      unsigned short sb1 = bc<unsigned short>((_Float16)scv1[d]);
      uint32_t u1 = (uint32_t)sb1;
      s2b[4 + d] = u1 | (u1 << 16);
    }
    floatx4 scn0 = scv0, scn1 = scv1;
    if (g + 1 < GROUPS) {
      scn0 = *(const floatx4*)sptr;
      scn1 = *(const floatx4*)(sptr + 64);
    }
    sptr += N_DIM;
#pragma unroll
    for (int tt = 0; tt < 4; ++tt) {
      const int t = g * 4 + tt;
      halfx8 afr[4];
#pragma unroll
      for (int mf = 0; mf < 4; ++mf) {
        const float* s0 = araw + (size_t)mf * 16 * K_DIM + (size_t)t * 32;
        floatx4 a0 = *(const floatx4*)s0;
        floatx4 a1 = *(const floatx4*)(s0 + 4);
        afr[mf][0] = (_Float16)a0[0]; afr[mf][1] = (_Float16)a1[0];
        afr[mf][2] = (_Float16)a0[1]; afr[mf][3] = (_Float16)a1[1];
        afr[mf][4] = (_Float16)a0[2]; afr[mf][5] = (_Float16)a1[2];
        afr[mf][6] = (_Float16)a0[3]; afr[mf][7] = (_Float16)a1[3];
      }
      uintx4 qna = q1a, qnb = q1b;
      if (t + 2 < STEPS) {
        qna = *(const uintx4*)qptr;
        qnb = *(const uintx4*)(qptr + 64);
      }
      qptr += 4 * (size_t)N_DIM;
#pragma unroll
      for (int d = 0; d < 4; ++d) {
        halfx8 b = dequant8(q0a[d], s2b[d]);
#pragma unroll
        for (int mf = 0; mf < 4; ++mf)
          acc[mf][d] = __builtin_amdgcn_mfma_f32_16x16x32_f16(afr[mf], b,
                                                              acc[mf][d], 0, 0, 0);
      }
#pragma unroll
      for (int d = 0; d < 4; ++d) {
        halfx8 b = dequant8(q0b[d], s2b[4 + d]);
#pragma unroll
        for (int mf = 0; mf < 4; ++mf)
          acc[mf][4 + d] = __builtin_amdgcn_mfma_f32_16x16x32_f16(afr[mf], b,
                                                                  acc[mf][4 + d], 0, 0, 0);
      }
      q0a = q1a; q0b = q1b;
      q1a = qna; q1b = qnb;
    }
    scv0 = scn0;
    scv1 = scn1;
  }
#pragma unroll
  for (int h = 0; h < 2; ++h) {
    const int nc = ncol + 64 * h;
    floatx4 bb = *(const floatx4*)(bias + nc);
#pragma unroll
    for (int mf = 0; mf < 4; ++mf) {
#pragma unroll
      for (int r = 0; r < 4; ++r) {
        const int m = mf * 16 + l4 * 4 + r;
        floatx4 v = {acc[mf][4 * h + 0][r] + bb.x, acc[mf][4 * h + 1][r] + bb.y,
                     acc[mf][4 * h + 2][r] + bb.z, acc[mf][4 * h + 3][r] + bb.w};
        *(floatx4*)(out + (size_t)m * N_DIM + nc) = v;
      }
    }
  }
}

// Sum KS fp32 partials, add fp32 bias, emit fp32.
template <int KS>
__global__ __launch_bounds__(256) void wq_reduce(const float* __restrict__ part,
                                                 const float* __restrict__ bias,
                                                 float* __restrict__ out) {
  const int idx = (int)blockIdx.x * 256 + (int)threadIdx.x;
  const int m = idx / (N_DIM / 4);
  const int n = (idx - m * (N_DIM / 4)) * 4;
  floatx4 s = (floatx4)(0.0f);
#pragma unroll
  for (int p = 0; p < KS; ++p)
    s += *(const floatx4*)(part + ((size_t)p * M_DIM + m) * N_DIM + n);
  floatx4 bb = *(const floatx4*)(bias + n);
  s += bb;
  *(floatx4*)(out + (size_t)m * N_DIM + n) = s;
}

extern "C" void kernel_launch(void* const* d_in, const int* in_sizes, int n_in,
                              void* d_out, int out_size, void* d_ws, size_t ws_size,
                              hipStream_t stream) {
  const float* A = (const float*)d_in[0];
  const int* qw = (const int*)d_in[1];
  const float* sc = (const float*)d_in[2];
  const float* bi = (const float*)d_in[3];
  float* out = (float*)d_out;

  char* ws = (char*)d_ws;
  const size_t packB = (size_t)M_DIM * K_DIM * sizeof(_Float16);  // 1 MiB
  const size_t mnB = (size_t)M_DIM * N_DIM * sizeof(float);       // 7.34 MB
  _Float16* Apack = (_Float16*)ws;
  float* part = (float*)(ws + packB);

  const int nblk = N_DIM / 512;                // 56 (4-wave 512n blocks)
  const int rblk = (M_DIM * N_DIM / 4) / 256;  // 1792

  if (ws_size >= packB + 8 * mnB) {
    // (56, 8) = 448 blocks x 4 waves = 1792 waves = 7 waves/CU
    pack_a<<<256, 256, 0, stream>>>(A, Apack);
    wq_lds<K_DIM / 8, true><<<dim3(nblk, 8), 256, 0, stream>>>(
        Apack, qw, sc, bi, part, out);
    wq_reduce<8><<<rblk, 256, 0, stream>>>(part, bi, out);
  } else if (ws_size >= packB + 4 * mnB) {
    pack_a<<<256, 256, 0, stream>>>(A, Apack);
    wq_lds<K_DIM / 4, true><<<dim3(nblk, 4), 256, 0, stream>>>(
        Apack, qw, sc, bi, part, out);
    wq_reduce<4><<<rblk, 256, 0, stream>>>(part, bi, out);
  } else if (ws_size >= packB + 2 * mnB) {
    pack_a<<<256, 256, 0, stream>>>(A, Apack);
    wq_lds<K_DIM / 2, true><<<dim3(nblk, 2), 256, 0, stream>>>(
        Apack, qw, sc, bi, part, out);
    wq_reduce<2><<<rblk, 256, 0, stream>>>(part, bi, out);
  } else if (ws_size >= packB) {
    pack_a<<<256, 256, 0, stream>>>(A, Apack);
    wq_lds<K_DIM, false><<<dim3(nblk, 1), 256, 0, stream>>>(
        Apack, qw, sc, bi, part, out);
  } else {
    wq_reg<<<dim3(N_DIM / 128, 1), 64, 0, stream>>>(A, qw, sc, bi, out);
  }
}